// Round 9
// baseline (83.501 us; speedup 1.0000x reference)
//
#include <hip/hip_runtime.h>
#include <hip/hip_bf16.h>

// Problem constants (B=4, L=4096, C=512, H=16, Dh=32, K=13)
#define BATCH   4
#define LSEQ    4096
#define CCH     512
#define HNUM    16
#define DH      32
#define KSZ     13
#define NHALF   6           // K/2
#define M_TOT   16384       // B*L
#define N_QKV   1536        // 3*C
#define KDIM    512         // C
#define BK      64          // proj GEMM K-step (unchanged R8 path)

typedef __attribute__((ext_vector_type(8))) short  short8;
typedef __attribute__((ext_vector_type(4))) short  short4_t;
typedef __attribute__((ext_vector_type(4))) float  float4_t;

__device__ __forceinline__ unsigned short f32_to_bf16(float f) {
    union { float f; unsigned int u; } un; un.f = f;
    unsigned int u = un.u;
    u += 0x7FFFu + ((u >> 16) & 1u);   // RNE (inputs are finite)
    return (unsigned short)(u >> 16);
}
__device__ __forceinline__ float bf16_to_f32(unsigned short h) {
    union { unsigned int u; float f; } un; un.u = ((unsigned int)h) << 16;
    return un.f;
}

// async global(16B/lane) -> LDS; lds base must be wave-uniform, HW adds lane*16
__device__ __forceinline__ void gload_lds16(const unsigned short* g, unsigned short* l) {
    __builtin_amdgcn_global_load_lds(
        (const __attribute__((address_space(1))) unsigned int*)g,
        (__attribute__((address_space(3))) unsigned int*)l,
        16, 0, 0);
}

// ---------------------------------------------------------------- cvt f32->bf16
// one launch converts x, qkv_w, proj_w (grid-stride over the 3 ranges)
__global__ void cvt_all(const float4_t* __restrict__ xin,  short4_t* __restrict__ xo,  int nx,
                        const float4_t* __restrict__ w1in, short4_t* __restrict__ w1o, int n1,
                        const float4_t* __restrict__ w2in, short4_t* __restrict__ w2o, int n2) {
    int i = blockIdx.x * blockDim.x + threadIdx.x;
    int stride = gridDim.x * blockDim.x;
    int ntot = nx + n1 + n2;
    for (; i < ntot; i += stride) {
        const float4_t* src; short4_t* dst; int j;
        if (i < nx)            { src = xin;  dst = xo;  j = i; }
        else if (i < nx + n1)  { src = w1in; dst = w1o; j = i - nx; }
        else                   { src = w2in; dst = w2o; j = i - nx - n1; }
        float4_t v = src[j];
        short4_t h;
        h.x = (short)f32_to_bf16(v.x);
        h.y = (short)f32_to_bf16(v.y);
        h.z = (short)f32_to_bf16(v.z);
        h.w = (short)f32_to_bf16(v.w);
        dst[j] = h;
    }
}

// ---------------------------------------------------------------- GEMM 1: QKV
// Xb (bf16, 16384x512) @ W^T (W bf16 1536x512) + bias -> qkv bf16 (3,B,H,L,Dh)
// BM=256 x BN=128, BK=32, 4 waves (2M x 2N), wave tile 128x64 (0.375
// ds_read/MFMA vs 0.5 at 64x64). 48KB double-buffered LDS -> 2 blocks/CU.
// Grid 64x12 = 768 = 3 clean rounds. Per tile: 2 phases, each {issue 3
// gloads of tile t+1 | ds_read | 16 MFMA in setprio}, vmcnt(3) gate (never
// 0 in-loop), 2 barriers/tile. XOR chunk swizzle domain 4 (2-way = free).
__global__ __launch_bounds__(256, 2) void gemm_qkv(
    const unsigned short* __restrict__ Xb,
    const unsigned short* __restrict__ W,
    const float* __restrict__ bias,
    unsigned short* __restrict__ qkvout)
{
    extern __shared__ __align__(16) unsigned short lds[];  // 49152 B
    // buf d (d=0,1): A @ d*12288 (256x32), B @ d*12288+8192 (128x32)
    const int tid  = threadIdx.x;
    const int wv   = tid >> 6, ln = tid & 63;
    const int m0   = blockIdx.x * 256;
    const int n0   = blockIdx.y * 128;
    const int wm   = (wv >> 1) * 128;         // 2 M-halves
    const int wn   = (wv & 1) * 64;           // 2 N-halves
    const int lr   = ln & 15;                 // fragment row/col
    const int lg   = ln >> 4;                 // k-group (0..3)
    const int r16  = ln >> 2;                 // staging: row within 16-row group
    const int csw4 = ((ln & 3) ^ (r16 & 3)) * 8;  // staging: swizzled chunk (elems)

    float4_t acc[8][4];
    #pragma unroll
    for (int m = 0; m < 8; ++m)
        #pragma unroll
        for (int n = 0; n < 4; ++n)
            acc[m][n] = (float4_t){0.f, 0.f, 0.f, 0.f};

    // stage half `h_` (0/1) of K-tile at col k0_ into buffer d_: 2 A + 1 B gloads
    #define STAGE_HALF(k0_, d_, h_) do {                                      \
        _Pragma("unroll")                                                     \
        for (int i_ = 0; i_ < 2; ++i_) {                                      \
            int g_ = wv * 4 + (h_) * 2 + i_;      /* A group 0..15 */         \
            gload_lds16(Xb + (size_t)(m0 + g_ * 16 + r16) * KDIM + (k0_) + csw4,\
                        lds + (d_) * 12288 + g_ * 512);                       \
        }                                                                     \
        {                                                                     \
            int g_ = wv * 2 + (h_);               /* B group 0..7 */          \
            gload_lds16(W + (size_t)(n0 + g_ * 16 + r16) * KDIM + (k0_) + csw4,\
                        lds + (d_) * 12288 + 8192 + g_ * 512);                \
        }                                                                     \
    } while (0)

    STAGE_HALF(0, 0, 0);
    STAGE_HALF(0, 0, 1);            // tile 0 fully issued (6 loads)

    #pragma unroll 2
    for (int t = 0; t < 16; ++t) {
        const int b = t & 1;
        const unsigned short* Ab = lds + b * 12288;
        const unsigned short* Bb = lds + b * 12288 + 8192;

        if (t < 15) {
            STAGE_HALF((t + 1) * 32, b ^ 1, 0);               // 3 loads (WAR-safe:
            asm volatile("s_waitcnt vmcnt(3)" ::: "memory");  //  gated by t-1 end-bar)
        } else {
            asm volatile("s_waitcnt vmcnt(0)" ::: "memory");  // final drain
        }
        __builtin_amdgcn_s_barrier();                         // tile t data ready

        // phase 0: B frags + A lower half, 16 MFMA
        short8 bfr[4], af[4];
        #pragma unroll
        for (int n = 0; n < 4; ++n) {
            int row = wn + n * 16 + lr;
            bfr[n] = *reinterpret_cast<const short8*>(
                &Bb[row * 32 + (lg ^ (row & 3)) * 8]);
        }
        #pragma unroll
        for (int m = 0; m < 4; ++m) {
            int row = wm + m * 16 + lr;
            af[m] = *reinterpret_cast<const short8*>(
                &Ab[row * 32 + (lg ^ (row & 3)) * 8]);
        }
        __builtin_amdgcn_s_setprio(1);
        #pragma unroll
        for (int m = 0; m < 4; ++m)
            #pragma unroll
            for (int n = 0; n < 4; ++n)
                acc[m][n] = __builtin_amdgcn_mfma_f32_16x16x32_bf16(
                    af[m], bfr[n], acc[m][n], 0, 0, 0);
        __builtin_amdgcn_s_setprio(0);
        __builtin_amdgcn_sched_barrier(0);

        if (t < 15) STAGE_HALF((t + 1) * 32, b ^ 1, 1);       // 3 more loads

        // phase 1: A upper half, 16 MFMA (reuse B frags)
        short8 af2[4];
        #pragma unroll
        for (int m = 0; m < 4; ++m) {
            int row = wm + 64 + m * 16 + lr;
            af2[m] = *reinterpret_cast<const short8*>(
                &Ab[row * 32 + (lg ^ (row & 3)) * 8]);
        }
        __builtin_amdgcn_s_setprio(1);
        #pragma unroll
        for (int m = 0; m < 4; ++m)
            #pragma unroll
            for (int n = 0; n < 4; ++n)
                acc[4 + m][n] = __builtin_amdgcn_mfma_f32_16x16x32_bf16(
                    af2[m], bfr[n], acc[4 + m][n], 0, 0, 0);
        __builtin_amdgcn_s_setprio(0);

        __builtin_amdgcn_s_barrier();     // end gate: reads of buf b done before
                                          // tile t+1 top refills buf b^1 readers
    }
    #undef STAGE_HALF

    // epilogue: bias, q-scale, scatter to (3,B,H,L,Dh) bf16
    const float qscale = 0.17677669529663687f;  // Dh^-0.5
    #pragma unroll
    for (int mf = 0; mf < 8; ++mf) {
        #pragma unroll
        for (int nf = 0; nf < 4; ++nf) {
            int gn    = n0 + wn + nf * 16 + lr;
            int which = gn >> 9;            // 0=q 1=k 2=v
            int hh    = (gn >> 5) & 15;
            int dd    = gn & 31;
            float bsv = bias[gn];
            #pragma unroll
            for (int r = 0; r < 4; ++r) {
                int gm = m0 + wm + mf * 16 + lg * 4 + r;
                float v = acc[mf][nf][r] + bsv;
                if (which == 0) v *= qscale;
                int b_ = gm >> 12, l = gm & 4095;
                size_t off = (((size_t)which * BATCH + b_) * HNUM + hh) *
                                 ((size_t)LSEQ * DH) + (size_t)l * DH + dd;
                qkvout[off] = f32_to_bf16(v);
            }
        }
    }
}

// ---------------------------------------------------------------- attention
// one block = (b, h, 256 consecutive l). K/V window staged in LDS as
// [cq][row][8] planes (16B row stride): lane-consecutive rows hit all 32 banks.
__global__ __launch_bounds__(256) void natten_fwd(
    const unsigned short* __restrict__ qkv,  // (3,B,H,L,Dh) bf16
    const float* __restrict__ rpb,           // (16,25) f32
    unsigned short* __restrict__ ctx)        // (B,L,C) bf16
{
    __shared__ __align__(16) unsigned short ks[4 * 268 * 8];
    __shared__ __align__(16) unsigned short vs[4 * 268 * 8];
    __shared__ float rpb_s[2 * KSZ - 1];

    const int t    = threadIdx.x;
    const int lblk = blockIdx.x & 15;       // L/256 = 16 chunks
    const int bh   = blockIdx.x >> 4;
    const int hh   = bh & 15, b_ = bh >> 4;
    const int l0   = lblk * 256;

    const int r0    = max(l0 - NHALF, 0);
    const int rend  = min(l0 + 256 + NHALF, LSEQ);
    const int nrows = rend - r0;            // <= 268

    const size_t plane = (size_t)LSEQ * DH;
    const size_t kbase = (((size_t)1 * BATCH + b_) * HNUM + hh) * plane;
    const size_t vbase = (((size_t)2 * BATCH + b_) * HNUM + hh) * plane;

    {
        const int cq  = t >> 6;
        const int rr  = t & 63;
        #pragma unroll
        for (int base = 0; base < 320; base += 64) {
            int row = base + rr;
            if (row < nrows) {
                *reinterpret_cast<short8*>(&ks[(cq * 268 + row) * 8]) =
                    *reinterpret_cast<const short8*>(&qkv[kbase + (size_t)(r0 + row) * DH + cq * 8]);
                *reinterpret_cast<short8*>(&vs[(cq * 268 + row) * 8]) =
                    *reinterpret_cast<const short8*>(&qkv[vbase + (size_t)(r0 + row) * DH + cq * 8]);
            }
        }
    }
    if (t < 2 * KSZ - 1) rpb_s[t] = rpb[hh * (2 * KSZ - 1) + t];
    __syncthreads();

    const int l = l0 + t;
    float q[DH];
    const size_t qoff = (((size_t)0 * BATCH + b_) * HNUM + hh) * plane + (size_t)l * DH;
    #pragma unroll
    for (int cq = 0; cq < 4; ++cq) {
        short8 qv = *reinterpret_cast<const short8*>(&qkv[qoff + cq * 8]);
        #pragma unroll
        for (int e = 0; e < 8; ++e) q[cq * 8 + e] = bf16_to_f32((unsigned short)qv[e]);
    }

    const int start = min(max(l - NHALF, 0), LSEQ - KSZ);
    float logit[KSZ];
    #pragma unroll
    for (int j = 0; j < KSZ; ++j) {
        int kr = start + j - r0;
        float s = 0.f;
        #pragma unroll
        for (int cq = 0; cq < 4; ++cq) {
            short8 kv = *reinterpret_cast<const short8*>(&ks[(cq * 268 + kr) * 8]);
            #pragma unroll
            for (int e = 0; e < 8; ++e)
                s += q[cq * 8 + e] * bf16_to_f32((unsigned short)kv[e]);
        }
        logit[j] = s + rpb_s[start + j - l + (KSZ - 1)];
    }
    float mx = logit[0];
    #pragma unroll
    for (int j = 1; j < KSZ; ++j) mx = fmaxf(mx, logit[j]);
    float p[KSZ], sum = 0.f;
    #pragma unroll
    for (int j = 0; j < KSZ; ++j) { p[j] = __expf(logit[j] - mx); sum += p[j]; }
    const float inv = 1.f / sum;

    float o[DH];
    #pragma unroll
    for (int d = 0; d < DH; ++d) o[d] = 0.f;
    #pragma unroll
    for (int j = 0; j < KSZ; ++j) {
        int kr = start + j - r0;
        float pj = p[j] * inv;
        #pragma unroll
        for (int cq = 0; cq < 4; ++cq) {
            short8 vv = *reinterpret_cast<const short8*>(&vs[(cq * 268 + kr) * 8]);
            #pragma unroll
            for (int e = 0; e < 8; ++e)
                o[cq * 8 + e] += pj * bf16_to_f32((unsigned short)vv[e]);
        }
    }
    const size_t obase = ((size_t)(b_ * LSEQ + l)) * CCH + hh * DH;
    #pragma unroll
    for (int cq = 0; cq < 4; ++cq) {
        short8 ov;
        #pragma unroll
        for (int e = 0; e < 8; ++e) ov[e] = (short)f32_to_bf16(o[cq * 8 + e]);
        *reinterpret_cast<short8*>(&ctx[obase + cq * 8]) = ov;
    }
}

// ---------------------------------------------------------------- GEMM 2: proj
// ctx (bf16, 16384x512) @ W^T (W bf16 512x512) + bias -> out f32 (B,L,C)
// R8 proven: R3 skeleton + 2-phase dbuf counted-vmcnt pipeline.
__global__ __launch_bounds__(256) void gemm_proj(
    const unsigned short* __restrict__ Xb,
    const unsigned short* __restrict__ W,
    const float* __restrict__ bias,
    float* __restrict__ out)
{
    extern __shared__ __align__(16) unsigned short lds[];  // 65536 B
    const int tid  = threadIdx.x;
    const int wv   = tid >> 6, ln = tid & 63;
    const int m0   = blockIdx.x * 128;
    const int n0   = blockIdx.y * 128;
    const int wm   = (wv >> 1) * 64;
    const int wn   = (wv & 1) * 64;
    const int lr   = ln & 15;
    const int lg   = ln >> 4;
    const int rgrp = ln >> 3;
    const int csw  = ((ln & 7) ^ rgrp) * 8;

    float4_t acc[4][4];
    #pragma unroll
    for (int m = 0; m < 4; ++m)
        #pragma unroll
        for (int n = 0; n < 4; ++n)
            acc[m][n] = (float4_t){0.f, 0.f, 0.f, 0.f};

    #define STAGEP(k0_, abuf_, bbuf_) do {                                    \
        _Pragma("unroll")                                                     \
        for (int it_ = 0; it_ < 4; ++it_) {                                   \
            int ch_  = it_ * 4 + wv;                                          \
            int row_ = ch_ * 8 + rgrp;                                        \
            gload_lds16(Xb + (size_t)(m0 + row_) * KDIM + (k0_) + csw,        \
                        (abuf_) + ch_ * 8 * BK);                              \
            gload_lds16(W  + (size_t)(n0 + row_) * KDIM + (k0_) + csw,        \
                        (bbuf_) + ch_ * 8 * BK);                              \
        }                                                                     \
    } while (0)

    unsigned short* Ac = lds;           unsigned short* Bc = lds + 8192;
    unsigned short* An = lds + 16384;   unsigned short* Bn = lds + 24576;

    STAGEP(0, Ac, Bc);

    for (int t = 0; t < 8; ++t) {
        if (t < 7) {
            STAGEP((t + 1) * BK, An, Bn);
            asm volatile("s_waitcnt vmcnt(8)" ::: "memory");
        } else {
            asm volatile("s_waitcnt vmcnt(0)" ::: "memory");
        }
        __builtin_amdgcn_s_barrier();

        short8 af[2][4], bfr[2][4];
        #pragma unroll
        for (int kk = 0; kk < 2; ++kk) {
            #pragma unroll
            for (int m = 0; m < 4; ++m) {
                int row = wm + m * 16 + lr;
                int c   = (kk * 4 + lg) ^ (row & 7);
                af[kk][m] = *reinterpret_cast<const short8*>(&Ac[row * BK + c * 8]);
            }
            #pragma unroll
            for (int n = 0; n < 4; ++n) {
                int row = wn + n * 16 + lr;
                int c   = (kk * 4 + lg) ^ (row & 7);
                bfr[kk][n] = *reinterpret_cast<const short8*>(&Bc[row * BK + c * 8]);
            }
        }
        #pragma unroll
        for (int kk = 0; kk < 2; ++kk)
            #pragma unroll
            for (int m = 0; m < 4; ++m)
                #pragma unroll
                for (int n = 0; n < 4; ++n)
                    acc[m][n] = __builtin_amdgcn_mfma_f32_16x16x32_bf16(
                        af[kk][m], bfr[kk][n], acc[m][n], 0, 0, 0);

        if (t < 7) __builtin_amdgcn_s_barrier();
        unsigned short* tA = Ac; Ac = An; An = tA;
        unsigned short* tB = Bc; Bc = Bn; Bn = tB;
    }
    #undef STAGEP

    #pragma unroll
    for (int m = 0; m < 4; ++m) {
        #pragma unroll
        for (int n = 0; n < 4; ++n) {
            int gn = n0 + wn + n * 16 + lr;
            float bsv = bias[gn];
            #pragma unroll
            for (int r = 0; r < 4; ++r) {
                int gm = m0 + wm + m * 16 + lg * 4 + r;
                out[(size_t)gm * CCH + gn] = acc[m][n][r] + bsv;
            }
        }
    }
}

// ---------------------------------------------------------------- launch
extern "C" void kernel_launch(void* const* d_in, const int* in_sizes, int n_in,
                              void* d_out, int out_size, void* d_ws, size_t ws_size,
                              hipStream_t stream) {
    const float* x      = (const float*)d_in[0];
    const float* qkv_w  = (const float*)d_in[1];
    const float* qkv_b  = (const float*)d_in[2];
    const float* rpb    = (const float*)d_in[3];
    const float* proj_w = (const float*)d_in[4];
    const float* proj_b = (const float*)d_in[5];
    float* out = (float*)d_out;
    char* ws = (char*)d_ws;

    // ws layout (bytes):
    //   qkv bf16 (3*B*H*L*Dh = 25165824 elems)   @ 0          : 50331648
    //   xb/ctx overlay (8388608 elems bf16)      @ 50331648   : 16777216
    //   qkv_w bf16 (786432 elems)                @ 67108864   :  1572864
    //   proj_w bf16 (262144 elems)               @ 68681728   :   524288
    unsigned short* qkv = (unsigned short*)(ws);
    unsigned short* xb  = (unsigned short*)(ws + 50331648);
    unsigned short* ctx = (unsigned short*)(ws + 50331648);
    unsigned short* wq  = (unsigned short*)(ws + 67108864);
    unsigned short* wp  = (unsigned short*)(ws + 68681728);

    // all f32->bf16 conversions in one launch
    cvt_all<<<2048, 256, 0, stream>>>(
        (const float4_t*)x,      (short4_t*)xb, M_TOT * KDIM / 4,
        (const float4_t*)qkv_w,  (short4_t*)wq, 786432 / 4,
        (const float4_t*)proj_w, (short4_t*)wp, 262144 / 4);

    dim3 g1(M_TOT / 256, N_QKV / 128);   // 64 x 12 = 768 blocks, 48KB LDS
    gemm_qkv<<<g1, 256, 49152, stream>>>(xb, wq, qkv_b, qkv);

    natten_fwd<<<BATCH * HNUM * (LSEQ / 256), 256, 0, stream>>>(qkv, rpb, ctx);

    dim3 g2(M_TOT / 128, CCH / 128);     // 128 x 4 = 512 blocks
    gemm_proj<<<g2, 256, 65536, stream>>>(ctx, wp, proj_b, out);
}

// Round 10
// 77.007 us; speedup vs baseline: 1.0843x; 1.0843x over previous
//
#include <hip/hip_runtime.h>
#include <hip/hip_bf16.h>

// Problem constants (B=4, L=4096, C=512, H=16, Dh=32, K=13)
#define BATCH   4
#define LSEQ    4096
#define CCH     512
#define HNUM    16
#define DH      32
#define KSZ     13
#define NHALF   6           // K/2
#define M_TOT   16384       // B*L
#define N_QKV   1536        // 3*C
#define KDIM    512         // C
#define BK      64          // GEMM K-step (128B rows, XOR-swizzle domain of 8 chunks)

typedef __attribute__((ext_vector_type(8))) short  short8;
typedef __attribute__((ext_vector_type(4))) short  short4_t;
typedef __attribute__((ext_vector_type(4))) float  float4_t;

__device__ __forceinline__ unsigned short f32_to_bf16(float f) {
    union { float f; unsigned int u; } un; un.f = f;
    unsigned int u = un.u;
    u += 0x7FFFu + ((u >> 16) & 1u);   // RNE (inputs are finite)
    return (unsigned short)(u >> 16);
}
__device__ __forceinline__ float bf16_to_f32(unsigned short h) {
    union { unsigned int u; float f; } un; un.u = ((unsigned int)h) << 16;
    return un.f;
}

// async global(16B/lane) -> LDS; lds base must be wave-uniform, HW adds lane*16
__device__ __forceinline__ void gload_lds16(const unsigned short* g, unsigned short* l) {
    __builtin_amdgcn_global_load_lds(
        (const __attribute__((address_space(1))) unsigned int*)g,
        (__attribute__((address_space(3))) unsigned int*)l,
        16, 0, 0);
}

// ---------------------------------------------------------------- cvt f32->bf16
// one launch converts x, qkv_w, proj_w (grid-stride over the 3 ranges)
__global__ void cvt_all(const float4_t* __restrict__ xin,  short4_t* __restrict__ xo,  int nx,
                        const float4_t* __restrict__ w1in, short4_t* __restrict__ w1o, int n1,
                        const float4_t* __restrict__ w2in, short4_t* __restrict__ w2o, int n2) {
    int i = blockIdx.x * blockDim.x + threadIdx.x;
    int stride = gridDim.x * blockDim.x;
    int ntot = nx + n1 + n2;
    for (; i < ntot; i += stride) {
        const float4_t* src; short4_t* dst; int j;
        if (i < nx)            { src = xin;  dst = xo;  j = i; }
        else if (i < nx + n1)  { src = w1in; dst = w1o; j = i - nx; }
        else                   { src = w2in; dst = w2o; j = i - nx - n1; }
        float4_t v = src[j];
        short4_t h;
        h.x = (short)f32_to_bf16(v.x);
        h.y = (short)f32_to_bf16(v.y);
        h.z = (short)f32_to_bf16(v.z);
        h.w = (short)f32_to_bf16(v.w);
        dst[j] = h;
    }
}

// ---------------------------------------------------------------- GEMM 1: QKV
// R8 exact (proven ~30us): 128x128, BK=64, 4 waves, dbuf + counted vmcnt(8),
// raw s_barrier, XOR chunk swizzle (0 conflicts measured).
__global__ __launch_bounds__(256) void gemm_qkv(
    const unsigned short* __restrict__ Xb,
    const unsigned short* __restrict__ W,
    const float* __restrict__ bias,
    unsigned short* __restrict__ qkvout)
{
    extern __shared__ __align__(16) unsigned short lds[];  // 65536 B
    const int tid  = threadIdx.x;
    const int wv   = tid >> 6, ln = tid & 63;
    const int m0   = blockIdx.x * 128;
    const int n0   = blockIdx.y * 128;
    const int wm   = (wv >> 1) * 64;
    const int wn   = (wv & 1) * 64;
    const int lr   = ln & 15;
    const int lg   = ln >> 4;
    const int rgrp = ln >> 3;
    const int csw  = ((ln & 7) ^ rgrp) * 8;

    float4_t acc[4][4];
    #pragma unroll
    for (int m = 0; m < 4; ++m)
        #pragma unroll
        for (int n = 0; n < 4; ++n)
            acc[m][n] = (float4_t){0.f, 0.f, 0.f, 0.f};

    #define STAGE(k0_, abuf_, bbuf_) do {                                     \
        _Pragma("unroll")                                                     \
        for (int it_ = 0; it_ < 4; ++it_) {                                   \
            int ch_  = it_ * 4 + wv;                                          \
            int row_ = ch_ * 8 + rgrp;                                        \
            gload_lds16(Xb + (size_t)(m0 + row_) * KDIM + (k0_) + csw,        \
                        (abuf_) + ch_ * 8 * BK);                              \
            gload_lds16(W  + (size_t)(n0 + row_) * KDIM + (k0_) + csw,        \
                        (bbuf_) + ch_ * 8 * BK);                              \
        }                                                                     \
    } while (0)

    unsigned short* Ac = lds;           unsigned short* Bc = lds + 8192;
    unsigned short* An = lds + 16384;   unsigned short* Bn = lds + 24576;

    STAGE(0, Ac, Bc);

    for (int t = 0; t < 8; ++t) {
        if (t < 7) {
            STAGE((t + 1) * BK, An, Bn);
            asm volatile("s_waitcnt vmcnt(8)" ::: "memory");
        } else {
            asm volatile("s_waitcnt vmcnt(0)" ::: "memory");
        }
        __builtin_amdgcn_s_barrier();

        short8 af[2][4], bfr[2][4];
        #pragma unroll
        for (int kk = 0; kk < 2; ++kk) {
            #pragma unroll
            for (int m = 0; m < 4; ++m) {
                int row = wm + m * 16 + lr;
                int c   = (kk * 4 + lg) ^ (row & 7);
                af[kk][m] = *reinterpret_cast<const short8*>(&Ac[row * BK + c * 8]);
            }
            #pragma unroll
            for (int n = 0; n < 4; ++n) {
                int row = wn + n * 16 + lr;
                int c   = (kk * 4 + lg) ^ (row & 7);
                bfr[kk][n] = *reinterpret_cast<const short8*>(&Bc[row * BK + c * 8]);
            }
        }
        #pragma unroll
        for (int kk = 0; kk < 2; ++kk)
            #pragma unroll
            for (int m = 0; m < 4; ++m)
                #pragma unroll
                for (int n = 0; n < 4; ++n)
                    acc[m][n] = __builtin_amdgcn_mfma_f32_16x16x32_bf16(
                        af[kk][m], bfr[kk][n], acc[m][n], 0, 0, 0);

        if (t < 7) __builtin_amdgcn_s_barrier();
        unsigned short* tA = Ac; Ac = An; An = tA;
        unsigned short* tB = Bc; Bc = Bn; Bn = tB;
    }
    #undef STAGE

    const float qscale = 0.17677669529663687f;  // Dh^-0.5
    #pragma unroll
    for (int m = 0; m < 4; ++m) {
        #pragma unroll
        for (int n = 0; n < 4; ++n) {
            int gn    = n0 + wn + n * 16 + lr;
            int which = gn >> 9;            // 0=q 1=k 2=v
            int hh    = (gn >> 5) & 15;
            int dd    = gn & 31;
            float bsv = bias[gn];
            #pragma unroll
            for (int r = 0; r < 4; ++r) {
                int gm = m0 + wm + m * 16 + lg * 4 + r;
                float v = acc[m][n][r] + bsv;
                if (which == 0) v *= qscale;
                int b_ = gm >> 12, l = gm & 4095;
                size_t off = (((size_t)which * BATCH + b_) * HNUM + hh) *
                                 ((size_t)LSEQ * DH) + (size_t)l * DH + dd;
                qkvout[off] = f32_to_bf16(v);
            }
        }
    }
}

// ---------------------------------------------------------------- attention (MFMA)
// Dh=32 == K of mfma_f32_16x16x32_bf16. Per 16-token q-tile: 13-wide band fits
// a 32-key window [k0, k0+32), k0 = l0-6 (unclamped -> 16-aligned rel offsets;
// OOB handled by clamped addresses + validity masks, p=0 at invalid keys).
//   QK^T: A=Q (row=lane&15 token, k=(lane>>4)*8+e dims), B=K (col=lane&15 key)
//         -> 2 MFMAs; S layout: key=lane&15, token=(lane>>4)*4+reg.
//   softmax: row-reduce over 16 lanes (shfl_xor 1..8) x 2 tiles; bias from LDS.
//   PV: A=P via 1KB wave-private LDS bounce ([tok][key32] bf16);
//       B=V^T staged per-block in LDS [dim][key_rel] (NRP=280, 2-way reads).
// Block = 256 thr (4 waves), 256 tokens; wave w owns q-tiles w*64+{0,16,32,48}.
__global__ __launch_bounds__(256) void natten_fwd(
    const unsigned short* __restrict__ qkv,  // (3,B,H,L,Dh) bf16
    const float* __restrict__ rpb,           // (16,25) f32
    unsigned short* __restrict__ ctx)        // (B,L,C) bf16
{
    #define NRP 280   // V^T key stride (276 used + pad)
    __shared__ __align__(16) unsigned short vt[DH * NRP];   // V^T [dim][key_rel]
    __shared__ __align__(16) unsigned short pl[4 * 16 * 32];// per-wave P [tok][key]
    __shared__ float rpb_s[25];

    const int t    = threadIdx.x;
    const int wv   = t >> 6, ln = t & 63;
    const int lblk = blockIdx.x & 15;
    const int bh   = blockIdx.x >> 4;
    const int hh   = bh & 15, b_ = bh >> 4;
    const int l0b  = lblk * 256;
    const int r0   = l0b - 6;               // may be negative (masked)

    const size_t plane = (size_t)LSEQ * DH;
    const size_t qbase = (((size_t)0 * BATCH + b_) * HNUM + hh) * plane;
    const size_t kbase = (((size_t)1 * BATCH + b_) * HNUM + hh) * plane;
    const size_t vbase = (((size_t)2 * BATCH + b_) * HNUM + hh) * plane;

    // stage V^T: 276 keys x 32 dims (clamped addresses; invalid keys masked later)
    for (int kr = t; kr < 276; kr += 256) {
        int ka = min(max(r0 + kr, 0), LSEQ - 1);
        #pragma unroll
        for (int cq = 0; cq < 4; ++cq) {
            short8 v = *reinterpret_cast<const short8*>(&qkv[vbase + (size_t)ka * DH + cq * 8]);
            #pragma unroll
            for (int e = 0; e < 8; ++e)
                vt[(cq * 8 + e) * NRP + kr] = (unsigned short)v[e];
        }
    }
    if (t < 25) rpb_s[t] = rpb[hh * 25 + t];
    __syncthreads();

    const int g = ln >> 4;      // k-chunk / token-group
    const int c = ln & 15;      // A-row / B-col lane index

    #pragma unroll
    for (int qi = 0; qi < 4; ++qi) {
        const int l0 = l0b + wv * 64 + qi * 16;
        const int k0 = l0 - 6;              // window start (unclamped)

        // ---- QK^T: direct global frags ----
        short8 qf = *reinterpret_cast<const short8*>(
            &qkv[qbase + (size_t)(l0 + c) * DH + g * 8]);
        int key0c = min(max(k0 + c, 0), LSEQ - 1);
        int key1c = min(max(k0 + 16 + c, 0), LSEQ - 1);
        short8 kf0 = *reinterpret_cast<const short8*>(
            &qkv[kbase + (size_t)key0c * DH + g * 8]);
        short8 kf1 = *reinterpret_cast<const short8*>(
            &qkv[kbase + (size_t)key1c * DH + g * 8]);
        float4_t s0 = (float4_t){0.f, 0.f, 0.f, 0.f};
        float4_t s1 = (float4_t){0.f, 0.f, 0.f, 0.f};
        s0 = __builtin_amdgcn_mfma_f32_16x16x32_bf16(qf, kf0, s0, 0, 0, 0);
        s1 = __builtin_amdgcn_mfma_f32_16x16x32_bf16(qf, kf1, s1, 0, 0, 0);

        // ---- softmax (rows = tokens g*4+r; cols = 16 lanes x 2 tiles) ----
        const int ka0 = k0 + c;             // unclamped key ids
        const int ka1 = k0 + 16 + c;
        #pragma unroll
        for (int r = 0; r < 4; ++r) {
            int tok = l0 + g * 4 + r;
            int st  = min(max(tok - NHALF, 0), LSEQ - KSZ);
            bool v0 = (ka0 >= st) && (ka0 < st + KSZ);
            bool v1 = (ka1 >= st) && (ka1 < st + KSZ);
            float b0 = rpb_s[min(max(ka0 - tok + 12, 0), 24)];
            float b1 = rpb_s[min(max(ka1 - tok + 12, 0), 24)];
            float x0 = v0 ? s0[r] + b0 : -1e30f;
            float x1 = v1 ? s1[r] + b1 : -1e30f;
            float m = fmaxf(x0, x1);
            #pragma unroll
            for (int d = 1; d < 16; d <<= 1) m = fmaxf(m, __shfl_xor(m, d));
            float e0 = v0 ? __expf(x0 - m) : 0.f;
            float e1 = v1 ? __expf(x1 - m) : 0.f;
            float s = e0 + e1;
            #pragma unroll
            for (int d = 1; d < 16; d <<= 1) s += __shfl_xor(s, d);
            float inv = 1.f / s;
            // write normalized P (bf16) to wave-private bounce
            pl[wv * 512 + (g * 4 + r) * 32 + c]      = f32_to_bf16(e0 * inv);
            pl[wv * 512 + (g * 4 + r) * 32 + 16 + c] = f32_to_bf16(e1 * inv);
        }

        // ---- PV: A=P (tok=lane&15, keys g*8..+7), B=V^T (dim=lane&15) ----
        short8 pa = *reinterpret_cast<const short8*>(
            &pl[wv * 512 + c * 32 + g * 8]);
        int k0rel = l0 - l0b;               // k0 - r0, multiple of 16
        short8 vb0 = *reinterpret_cast<const short8*>(
            &vt[c * NRP + k0rel + g * 8]);
        short8 vb1 = *reinterpret_cast<const short8*>(
            &vt[(16 + c) * NRP + k0rel + g * 8]);
        float4_t o0 = (float4_t){0.f, 0.f, 0.f, 0.f};
        float4_t o1 = (float4_t){0.f, 0.f, 0.f, 0.f};
        o0 = __builtin_amdgcn_mfma_f32_16x16x32_bf16(pa, vb0, o0, 0, 0, 0);
        o1 = __builtin_amdgcn_mfma_f32_16x16x32_bf16(pa, vb1, o1, 0, 0, 0);

        // ---- store ctx (token=(lane>>4)*4+r, dim=lane&15 per tile) ----
        #pragma unroll
        for (int r = 0; r < 4; ++r) {
            size_t ob = ((size_t)(b_ * LSEQ + l0 + g * 4 + r)) * CCH + hh * DH;
            ctx[ob + c]      = f32_to_bf16(o0[r]);
            ctx[ob + 16 + c] = f32_to_bf16(o1[r]);
        }
    }
    #undef NRP
}

// ---------------------------------------------------------------- GEMM 2: proj
// ctx (bf16, 16384x512) @ W^T (W bf16 512x512) + bias -> out f32 (B,L,C)
// R8 proven: R3 skeleton + 2-phase dbuf counted-vmcnt pipeline.
__global__ __launch_bounds__(256) void gemm_proj(
    const unsigned short* __restrict__ Xb,
    const unsigned short* __restrict__ W,
    const float* __restrict__ bias,
    float* __restrict__ out)
{
    extern __shared__ __align__(16) unsigned short lds[];  // 65536 B
    const int tid  = threadIdx.x;
    const int wv   = tid >> 6, ln = tid & 63;
    const int m0   = blockIdx.x * 128;
    const int n0   = blockIdx.y * 128;
    const int wm   = (wv >> 1) * 64;
    const int wn   = (wv & 1) * 64;
    const int lr   = ln & 15;
    const int lg   = ln >> 4;
    const int rgrp = ln >> 3;
    const int csw  = ((ln & 7) ^ rgrp) * 8;

    float4_t acc[4][4];
    #pragma unroll
    for (int m = 0; m < 4; ++m)
        #pragma unroll
        for (int n = 0; n < 4; ++n)
            acc[m][n] = (float4_t){0.f, 0.f, 0.f, 0.f};

    #define STAGEP(k0_, abuf_, bbuf_) do {                                    \
        _Pragma("unroll")                                                     \
        for (int it_ = 0; it_ < 4; ++it_) {                                   \
            int ch_  = it_ * 4 + wv;                                          \
            int row_ = ch_ * 8 + rgrp;                                        \
            gload_lds16(Xb + (size_t)(m0 + row_) * KDIM + (k0_) + csw,        \
                        (abuf_) + ch_ * 8 * BK);                              \
            gload_lds16(W  + (size_t)(n0 + row_) * KDIM + (k0_) + csw,        \
                        (bbuf_) + ch_ * 8 * BK);                              \
        }                                                                     \
    } while (0)

    unsigned short* Ac = lds;           unsigned short* Bc = lds + 8192;
    unsigned short* An = lds + 16384;   unsigned short* Bn = lds + 24576;

    STAGEP(0, Ac, Bc);

    for (int t = 0; t < 8; ++t) {
        if (t < 7) {
            STAGEP((t + 1) * BK, An, Bn);
            asm volatile("s_waitcnt vmcnt(8)" ::: "memory");
        } else {
            asm volatile("s_waitcnt vmcnt(0)" ::: "memory");
        }
        __builtin_amdgcn_s_barrier();

        short8 af[2][4], bfr[2][4];
        #pragma unroll
        for (int kk = 0; kk < 2; ++kk) {
            #pragma unroll
            for (int m = 0; m < 4; ++m) {
                int row = wm + m * 16 + lr;
                int c   = (kk * 4 + lg) ^ (row & 7);
                af[kk][m] = *reinterpret_cast<const short8*>(&Ac[row * BK + c * 8]);
            }
            #pragma unroll
            for (int n = 0; n < 4; ++n) {
                int row = wn + n * 16 + lr;
                int c   = (kk * 4 + lg) ^ (row & 7);
                bfr[kk][n] = *reinterpret_cast<const short8*>(&Bc[row * BK + c * 8]);
            }
        }
        #pragma unroll
        for (int kk = 0; kk < 2; ++kk)
            #pragma unroll
            for (int m = 0; m < 4; ++m)
                #pragma unroll
                for (int n = 0; n < 4; ++n)
                    acc[m][n] = __builtin_amdgcn_mfma_f32_16x16x32_bf16(
                        af[kk][m], bfr[kk][n], acc[m][n], 0, 0, 0);

        if (t < 7) __builtin_amdgcn_s_barrier();
        unsigned short* tA = Ac; Ac = An; An = tA;
        unsigned short* tB = Bc; Bc = Bn; Bn = tB;
    }
    #undef STAGEP

    #pragma unroll
    for (int m = 0; m < 4; ++m) {
        #pragma unroll
        for (int n = 0; n < 4; ++n) {
            int gn = n0 + wn + n * 16 + lr;
            float bsv = bias[gn];
            #pragma unroll
            for (int r = 0; r < 4; ++r) {
                int gm = m0 + wm + m * 16 + lg * 4 + r;
                out[(size_t)gm * CCH + gn] = acc[m][n][r] + bsv;
            }
        }
    }
}

// ---------------------------------------------------------------- launch
extern "C" void kernel_launch(void* const* d_in, const int* in_sizes, int n_in,
                              void* d_out, int out_size, void* d_ws, size_t ws_size,
                              hipStream_t stream) {
    const float* x      = (const float*)d_in[0];
    const float* qkv_w  = (const float*)d_in[1];
    const float* qkv_b  = (const float*)d_in[2];
    const float* rpb    = (const float*)d_in[3];
    const float* proj_w = (const float*)d_in[4];
    const float* proj_b = (const float*)d_in[5];
    float* out = (float*)d_out;
    char* ws = (char*)d_ws;

    // ws layout (bytes):
    //   qkv bf16 (3*B*H*L*Dh = 25165824 elems)   @ 0          : 50331648
    //   xb/ctx overlay (8388608 elems bf16)      @ 50331648   : 16777216
    //   qkv_w bf16 (786432 elems)                @ 67108864   :  1572864
    //   proj_w bf16 (262144 elems)               @ 68681728   :   524288
    unsigned short* qkv = (unsigned short*)(ws);
    unsigned short* xb  = (unsigned short*)(ws + 50331648);
    unsigned short* ctx = (unsigned short*)(ws + 50331648);
    unsigned short* wq  = (unsigned short*)(ws + 67108864);
    unsigned short* wp  = (unsigned short*)(ws + 68681728);

    // all f32->bf16 conversions in one launch
    cvt_all<<<2048, 256, 0, stream>>>(
        (const float4_t*)x,      (short4_t*)xb, M_TOT * KDIM / 4,
        (const float4_t*)qkv_w,  (short4_t*)wq, 786432 / 4,
        (const float4_t*)proj_w, (short4_t*)wp, 262144 / 4);

    dim3 g1(M_TOT / 128, N_QKV / 128);   // 128 x 12 = 1536 blocks
    gemm_qkv<<<g1, 256, 65536, stream>>>(xb, wq, qkv_b, qkv);

    natten_fwd<<<BATCH * HNUM * (LSEQ / 256), 256, 0, stream>>>(qkv, rpb, ctx);

    dim3 g2(M_TOT / 128, CCH / 128);     // 128 x 4 = 512 blocks
    gemm_proj<<<g2, 256, 65536, stream>>>(ctx, wp, proj_b, out);
}